// Round 2
// baseline (274.711 us; speedup 1.0000x reference)
//
#include <hip/hip_runtime.h>
#include <math.h>

#define M_GRID 128
#define J_FEAT 80
#define NBASE  2
#define NNET   160   // NBASE*J_FEAT
#define HDIM   256
#define BATCH  2048

typedef __attribute__((ext_vector_type(8))) short v8s;  // 8 bf16 (4 VGPRs)
typedef __attribute__((ext_vector_type(4))) float f4;   // MFMA accum

__device__ __forceinline__ unsigned short f2bf(float f) {
    unsigned u = __float_as_uint(f);
    u += 0x7fffu + ((u >> 16) & 1u);   // round-to-nearest-even
    return (unsigned short)(u >> 16);
}

__device__ __forceinline__ float selu_f(float x) {
    const float SC = 1.0507009873554805f;
    const float AL = 1.6732632423543772f;
    return x > 0.f ? SC * x : SC * AL * (__expf(x) - 1.f);
}

// One workgroup per network n. 8 waves; wave w owns rows 16w..16w+15.
// Activations stay in registers (MFMA A-fragments, bf16); weights are staged
// per-layer into LDS as bf16, transposed to [j][k] (k contiguous), in two
// K-halves of 64 KiB each. Scratch for the C-layout -> A-layout transpose
// after LN/SELU aliases the same LDS (barrier-protected).
//
// launch_bounds(512,1): round-1 used (512,2) which capped VGPRs at 128 and
// spilled ~188 MB of accumulator traffic to scratch (WRITE_SIZE evidence).
// Grid is 160 blocks on 256 CUs, so >1 block/CU never happens anyway.
__launch_bounds__(512, 1)
__global__ void basis_kernel(const float* __restrict__ t,
                             const float* __restrict__ W_in,
                             const float* __restrict__ b_in,
                             const float* __restrict__ W_h,
                             const float* __restrict__ b_h,
                             const float* __restrict__ W_out,
                             const float* __restrict__ b_out,
                             const float* __restrict__ ln_a,
                             const float* __restrict__ ln_b,
                             float* __restrict__ basesT)   // [M][NNET]
{
    __shared__ __align__(16) unsigned char lds[65536];
    const int n   = blockIdx.x;
    const int tid = threadIdx.x;
    const int l   = tid & 63;
    const int wv  = tid >> 6;      // wave 0..7
    const int lr  = l & 15;
    const int g   = l >> 4;        // k-group for A/B fragments

    // ---------------- input layer, directly in A-layout ----------------
    // lane holds h = kt*32 + g*8 + i  for row (16*wv + lr)
    const int mrow = wv * 16 + lr;
    const float tval = t[mrow];

    float z[8][8];
    {
        const float* wi = W_in + (size_t)n * HDIM;
        const float* bi = b_in + (size_t)n * HDIM;
        #pragma unroll
        for (int kt = 0; kt < 8; ++kt) {
            const int h0 = kt * 32 + g * 8;
            #pragma unroll
            for (int i = 0; i < 8; ++i)
                z[kt][i] = tval * wi[h0 + i] + bi[h0 + i];
        }
    }
    {
        float s = 0.f, q = 0.f;
        #pragma unroll
        for (int kt = 0; kt < 8; ++kt)
            #pragma unroll
            for (int i = 0; i < 8; ++i) { float v = z[kt][i]; s += v; q += v * v; }
        // row's 256 values live in lanes l, l^16, l^32 (and ^48)
        s += __shfl_xor(s, 16); q += __shfl_xor(q, 16);
        s += __shfl_xor(s, 32); q += __shfl_xor(q, 32);
        const float mean = s * (1.f / 256.f);
        const float var  = (q - s * s * (1.f / 256.f)) * (1.f / 255.f); // unbiased
        const float inv  = 1.f / (sqrtf(var) + 1e-6f);                  // eps on std
        const float* la = ln_a + (size_t)n * HDIM;  // layer 0
        const float* lb = ln_b + (size_t)n * HDIM;
        #pragma unroll
        for (int kt = 0; kt < 8; ++kt) {
            const int h0 = kt * 32 + g * 8;
            #pragma unroll
            for (int i = 0; i < 8; ++i) {
                float v  = z[kt][i];
                float ln = (v - mean) * inv * la[h0 + i] + lb[h0 + i];
                z[kt][i] = selu_f(v + ln);
            }
        }
    }
    v8s afrag[8];
    #pragma unroll
    for (int kt = 0; kt < 8; ++kt) {
        v8s a;
        #pragma unroll
        for (int i = 0; i < 8; ++i) a[i] = (short)f2bf(z[kt][i]);
        afrag[kt] = a;
    }

    unsigned short* scr = (unsigned short*)lds + (size_t)wv * 4096; // 16x256 bf16

    // ---------------- 3 hidden layers ----------------
    #pragma unroll 1
    for (int L = 0; L < 3; ++L) {
        const float* Wl = W_h + ((size_t)L * NNET + n) * (HDIM * HDIM);
        f4 acc[16];
        const f4 zero = {0.f, 0.f, 0.f, 0.f};
        #pragma unroll
        for (int ct = 0; ct < 16; ++ct) acc[ct] = zero;

        #pragma unroll
        for (int hf = 0; hf < 2; ++hf) {
            __syncthreads();   // prior LDS readers done before we overwrite
            // stage W[hf*128 .. +127][0..255] -> lds as bf16 WT[j][k'] (k' contig)
            {
                const int j  = tid & 255;
                const int o8 = tid >> 8;                 // 0/1
                const float* src = Wl + (size_t)(hf * 128) * HDIM + j;
                #pragma unroll
                for (int oi = 0; oi < 8; ++oi) {
                    const int k8 = (o8 * 8 + oi) * 8;    // local k octet base
                    v8s pk;
                    #pragma unroll
                    for (int i = 0; i < 8; ++i)
                        pk[i] = (short)f2bf(src[(size_t)(k8 + i) * HDIM]);
                    const int byte = ((j * 128 + k8) * 2) ^ ((j & 7) << 4);
                    *(v8s*)(lds + byte) = pk;
                }
            }
            __syncthreads();
            // MFMA over this half's 4 k-tiles
            #pragma unroll
            for (int kk = 0; kk < 4; ++kk) {
                #pragma unroll
                for (int ct = 0; ct < 16; ++ct) {
                    const int j = ct * 16 + lr;
                    const int byte = ((j * 128 + (kk * 32 + g * 8)) * 2) ^ ((j & 7) << 4);
                    v8s bfrag = *(const v8s*)(lds + byte);
                    acc[ct] = __builtin_amdgcn_mfma_f32_16x16x32_bf16(
                        afrag[hf * 4 + kk], bfrag, acc[ct], 0, 0, 0);
                }
            }
        }
        __syncthreads();   // all WT reads done; scratch may now alias

        // C layout: acc[ct][r] = Znew[row=4g+r][col=ct*16+lr]
        const float* bh = b_h  + ((size_t)L * NNET + n) * HDIM;
        const float* la = ln_a + ((size_t)(L + 1) * NNET + n) * HDIM;
        const float* lb = ln_b + ((size_t)(L + 1) * NNET + n) * HDIM;

        float sums[4] = {0, 0, 0, 0}, sqs[4] = {0, 0, 0, 0};
        #pragma unroll
        for (int ct = 0; ct < 16; ++ct) {
            const float bias = bh[ct * 16 + lr];
            #pragma unroll
            for (int r = 0; r < 4; ++r) {
                float v = acc[ct][r] + bias;
                acc[ct][r] = v;
                sums[r] += v; sqs[r] += v * v;
            }
        }
        #pragma unroll
        for (int r = 0; r < 4; ++r) {
            #pragma unroll
            for (int msk = 1; msk <= 8; msk <<= 1) {
                sums[r] += __shfl_xor(sums[r], msk);
                sqs[r]  += __shfl_xor(sqs[r],  msk);
            }
        }
        float mean[4], inv[4];
        #pragma unroll
        for (int r = 0; r < 4; ++r) {
            mean[r] = sums[r] * (1.f / 256.f);
            float var = (sqs[r] - sums[r] * sums[r] * (1.f / 256.f)) * (1.f / 255.f);
            inv[r] = 1.f / (sqrtf(var) + 1e-6f);
        }

        if (L < 2) {
            #pragma unroll
            for (int ct = 0; ct < 16; ++ct) {
                const float a_ = la[ct * 16 + lr], b_ = lb[ct * 16 + lr];
                #pragma unroll
                for (int r = 0; r < 4; ++r) {
                    float v = acc[ct][r];
                    float s = selu_f(v + (v - mean[r]) * inv[r] * a_ + b_);
                    scr[(g * 4 + r) * 256 + (ct * 16 + lr)] = f2bf(s);
                }
            }
            __syncthreads();   // make writes visible (and fence the compiler)
            #pragma unroll
            for (int kt = 0; kt < 8; ++kt)
                afrag[kt] = *(const v8s*)((const unsigned char*)scr
                                          + (lr * 256 + kt * 32 + g * 8) * 2);
        } else {
            // fused output layer: bases[m] = sum_h z[m][h]*W_out[n][h] + b_out
            const float* wo = W_out + (size_t)n * HDIM;
            float ps[4] = {0, 0, 0, 0};
            #pragma unroll
            for (int ct = 0; ct < 16; ++ct) {
                const float a_ = la[ct * 16 + lr], b_ = lb[ct * 16 + lr];
                const float w_ = wo[ct * 16 + lr];
                #pragma unroll
                for (int r = 0; r < 4; ++r) {
                    float v = acc[ct][r];
                    float s = selu_f(v + (v - mean[r]) * inv[r] * a_ + b_);
                    ps[r] += s * w_;
                }
            }
            #pragma unroll
            for (int r = 0; r < 4; ++r)
                #pragma unroll
                for (int msk = 1; msk <= 8; msk <<= 1)
                    ps[r] += __shfl_xor(ps[r], msk);
            const float bo = b_out[n];
            #pragma unroll
            for (int r = 0; r < 4; ++r)
                if (lr == r)
                    basesT[(size_t)(wv * 16 + g * 4 + r) * NNET + n] = ps[r] + bo;
        }
    }
}

// score[b, jk] = sum_m x[b,m,jk>>1] * basesT[m][jk] * w[m]
// block: 32 jk-lanes x 8 batch rows; bases*w slice staged in LDS once.
__launch_bounds__(256)
__global__ void score_kernel(const float* __restrict__ x,
                             const float* __restrict__ t,
                             const float* __restrict__ basesT,
                             float* __restrict__ out)
{
    __shared__ float c_lds[M_GRID * 32];
    const int jt  = blockIdx.x;   // 0..4
    const int bt  = blockIdx.y;   // 0..255
    const int tid = threadIdx.x;

    for (int i = tid; i < M_GRID * 32; i += 256) {
        const int m  = i >> 5;
        const int jl = i & 31;
        const float tp = t[m == M_GRID - 1 ? M_GRID - 1 : m + 1];
        const float tm = t[m == 0 ? 0 : m - 1];
        c_lds[i] = basesT[(size_t)m * NNET + jt * 32 + jl] * 0.5f * (tp - tm);
    }
    __syncthreads();

    const int jj = tid & 31;
    const int bs = tid >> 5;
    const int jk = jt * 32 + jj;
    const int b  = bt * 8 + bs;
    const float* xp = x + (size_t)b * (M_GRID * J_FEAT) + (jk >> 1);
    float acc = 0.f;
    #pragma unroll 8
    for (int m = 0; m < M_GRID; ++m)
        acc += xp[(size_t)m * J_FEAT] * c_lds[m * 32 + jj];
    out[(size_t)b * NNET + jk] = acc;
}

extern "C" void kernel_launch(void* const* d_in, const int* in_sizes, int n_in,
                              void* d_out, int out_size, void* d_ws, size_t ws_size,
                              hipStream_t stream)
{
    const float* x     = (const float*)d_in[0];
    const float* t     = (const float*)d_in[1];
    const float* W_in  = (const float*)d_in[2];
    const float* b_in  = (const float*)d_in[3];
    const float* W_h   = (const float*)d_in[4];
    const float* b_h   = (const float*)d_in[5];
    const float* W_out = (const float*)d_in[6];
    const float* b_out = (const float*)d_in[7];
    const float* ln_a  = (const float*)d_in[8];
    const float* ln_b  = (const float*)d_in[9];
    float* basesT = (float*)d_ws;   // 128*160*4 = 80 KiB

    basis_kernel<<<dim3(NNET), dim3(512), 0, stream>>>(
        t, W_in, b_in, W_h, b_h, W_out, b_out, ln_a, ln_b, basesT);
    score_kernel<<<dim3(5, 256), dim3(256), 0, stream>>>(
        x, t, basesT, (float*)d_out);
}

// Round 3
// 111.283 us; speedup vs baseline: 2.4686x; 2.4686x over previous
//
#include <hip/hip_runtime.h>
#include <math.h>

#define M_GRID 128
#define J_FEAT 80
#define NBASE  2
#define NNET   160   // NBASE*J_FEAT
#define HDIM   256
#define BATCH  2048

typedef __attribute__((ext_vector_type(8))) short v8s;  // 8 bf16 (4 VGPRs)
typedef __attribute__((ext_vector_type(4))) float f4;   // MFMA accum

__device__ __forceinline__ unsigned short f2bf(float f) {
    unsigned u = __float_as_uint(f);
    u += 0x7fffu + ((u >> 16) & 1u);   // round-to-nearest-even
    return (unsigned short)(u >> 16);
}

__device__ __forceinline__ float selu_f(float x) {
    const float SC = 1.0507009873554805f;
    const float AL = 1.6732632423543772f;
    return x > 0.f ? SC * x : SC * AL * (__expf(x) - 1.f);
}

// One workgroup per network n. 8 waves; wave w owns rows 16w..16w+15.
// Activations stay in registers (MFMA A-fragments, bf16); weights are staged
// per-layer into LDS as bf16, transposed to [j][k] (k contiguous), in two
// K-halves of 64 KiB each.
//
// Register-budget handling (rounds 1-2 post-mortem): __launch_bounds__ left
// the kernel at a 128-VGPR budget and ~188 MB of scratch spill traffic
// (WRITE_SIZE evidence) dominated runtime. Here:
//  - amdgpu_waves_per_eu(1,2): 8-wave block on a CU = 2 waves/SIMD -> allow
//    up to 256 VGPRs/wave (512-reg unified file / 2 waves).
//  - acc[] pinned to AGPRs via a no-op "+a" asm, moving 64 regs to the
//    accumulator side of the unified file.
//  - staging gather loop unroll capped at 2 to limit in-flight loads.
__attribute__((amdgpu_flat_work_group_size(512, 512), amdgpu_waves_per_eu(1, 2)))
__global__ void basis_kernel(const float* __restrict__ t,
                             const float* __restrict__ W_in,
                             const float* __restrict__ b_in,
                             const float* __restrict__ W_h,
                             const float* __restrict__ b_h,
                             const float* __restrict__ W_out,
                             const float* __restrict__ b_out,
                             const float* __restrict__ ln_a,
                             const float* __restrict__ ln_b,
                             float* __restrict__ basesT)   // [M][NNET]
{
    __shared__ __align__(16) unsigned char lds[65536];
    const int n   = blockIdx.x;
    const int tid = threadIdx.x;
    const int l   = tid & 63;
    const int wv  = tid >> 6;      // wave 0..7
    const int lr  = l & 15;
    const int g   = l >> 4;        // k-group for A/B fragments

    // ---------------- input layer, directly in A-layout ----------------
    // lane holds h = kt*32 + g*8 + i  for row (16*wv + lr)
    const int mrow = wv * 16 + lr;
    const float tval = t[mrow];

    float z[8][8];
    {
        const float* wi = W_in + (size_t)n * HDIM;
        const float* bi = b_in + (size_t)n * HDIM;
        #pragma unroll
        for (int kt = 0; kt < 8; ++kt) {
            const int h0 = kt * 32 + g * 8;
            #pragma unroll
            for (int i = 0; i < 8; ++i)
                z[kt][i] = tval * wi[h0 + i] + bi[h0 + i];
        }
    }
    {
        float s = 0.f, q = 0.f;
        #pragma unroll
        for (int kt = 0; kt < 8; ++kt)
            #pragma unroll
            for (int i = 0; i < 8; ++i) { float v = z[kt][i]; s += v; q += v * v; }
        // row's 256 values live in lanes l, l^16, l^32 (and ^48)
        s += __shfl_xor(s, 16); q += __shfl_xor(q, 16);
        s += __shfl_xor(s, 32); q += __shfl_xor(q, 32);
        const float mean = s * (1.f / 256.f);
        const float var  = (q - s * s * (1.f / 256.f)) * (1.f / 255.f); // unbiased
        const float inv  = 1.f / (sqrtf(var) + 1e-6f);                  // eps on std
        const float* la = ln_a + (size_t)n * HDIM;  // layer 0
        const float* lb = ln_b + (size_t)n * HDIM;
        #pragma unroll
        for (int kt = 0; kt < 8; ++kt) {
            const int h0 = kt * 32 + g * 8;
            #pragma unroll
            for (int i = 0; i < 8; ++i) {
                float v  = z[kt][i];
                float ln = (v - mean) * inv * la[h0 + i] + lb[h0 + i];
                z[kt][i] = selu_f(v + ln);
            }
        }
    }
    v8s afrag[8];
    #pragma unroll
    for (int kt = 0; kt < 8; ++kt) {
        v8s a;
        #pragma unroll
        for (int i = 0; i < 8; ++i) a[i] = (short)f2bf(z[kt][i]);
        afrag[kt] = a;
    }

    unsigned short* scr = (unsigned short*)lds + (size_t)wv * 4096; // 16x256 bf16

    // ---------------- 3 hidden layers ----------------
    #pragma unroll 1
    for (int L = 0; L < 3; ++L) {
        const float* Wl = W_h + ((size_t)L * NNET + n) * (HDIM * HDIM);
        f4 acc[16];
        const f4 zero = {0.f, 0.f, 0.f, 0.f};
        #pragma unroll
        for (int ct = 0; ct < 16; ++ct) acc[ct] = zero;
        // Pin accumulators to the AGPR side of the gfx950 unified file.
        #pragma unroll
        for (int ct = 0; ct < 16; ++ct)
            asm volatile("" : "+a"(acc[ct]));

        #pragma unroll
        for (int hf = 0; hf < 2; ++hf) {
            __syncthreads();   // prior LDS readers done before we overwrite
            // stage W[hf*128 .. +127][0..255] -> lds as bf16 WT[j][k'] (k' contig)
            {
                const int j  = tid & 255;
                const int o8 = tid >> 8;                 // 0/1
                const float* src = Wl + (size_t)(hf * 128) * HDIM + j;
                #pragma unroll 2
                for (int oi = 0; oi < 8; ++oi) {
                    const int k8 = (o8 * 8 + oi) * 8;    // local k octet base
                    v8s pk;
                    #pragma unroll
                    for (int i = 0; i < 8; ++i)
                        pk[i] = (short)f2bf(src[(size_t)(k8 + i) * HDIM]);
                    const int byte = ((j * 128 + k8) * 2) ^ ((j & 7) << 4);
                    *(v8s*)(lds + byte) = pk;
                }
            }
            __syncthreads();
            // MFMA over this half's 4 k-tiles
            #pragma unroll
            for (int kk = 0; kk < 4; ++kk) {
                #pragma unroll
                for (int ct = 0; ct < 16; ++ct) {
                    const int j = ct * 16 + lr;
                    const int byte = ((j * 128 + (kk * 32 + g * 8)) * 2) ^ ((j & 7) << 4);
                    v8s bfrag = *(const v8s*)(lds + byte);
                    acc[ct] = __builtin_amdgcn_mfma_f32_16x16x32_bf16(
                        afrag[hf * 4 + kk], bfrag, acc[ct], 0, 0, 0);
                }
            }
        }
        __syncthreads();   // all WT reads done; scratch may now alias

        // C layout: acc[ct][r] = Znew[row=4g+r][col=ct*16+lr]
        const float* bh = b_h  + ((size_t)L * NNET + n) * HDIM;
        const float* la = ln_a + ((size_t)(L + 1) * NNET + n) * HDIM;
        const float* lb = ln_b + ((size_t)(L + 1) * NNET + n) * HDIM;

        float sums[4] = {0, 0, 0, 0}, sqs[4] = {0, 0, 0, 0};
        #pragma unroll
        for (int ct = 0; ct < 16; ++ct) {
            const float bias = bh[ct * 16 + lr];
            #pragma unroll
            for (int r = 0; r < 4; ++r) {
                float v = acc[ct][r] + bias;
                acc[ct][r] = v;
                sums[r] += v; sqs[r] += v * v;
            }
        }
        #pragma unroll
        for (int r = 0; r < 4; ++r) {
            #pragma unroll
            for (int msk = 1; msk <= 8; msk <<= 1) {
                sums[r] += __shfl_xor(sums[r], msk);
                sqs[r]  += __shfl_xor(sqs[r],  msk);
            }
        }
        float mean[4], inv[4];
        #pragma unroll
        for (int r = 0; r < 4; ++r) {
            mean[r] = sums[r] * (1.f / 256.f);
            float var = (sqs[r] - sums[r] * sums[r] * (1.f / 256.f)) * (1.f / 255.f);
            inv[r] = 1.f / (sqrtf(var) + 1e-6f);
        }

        if (L < 2) {
            #pragma unroll
            for (int ct = 0; ct < 16; ++ct) {
                const float a_ = la[ct * 16 + lr], b_ = lb[ct * 16 + lr];
                #pragma unroll
                for (int r = 0; r < 4; ++r) {
                    float v = acc[ct][r];
                    float s = selu_f(v + (v - mean[r]) * inv[r] * a_ + b_);
                    scr[(g * 4 + r) * 256 + (ct * 16 + lr)] = f2bf(s);
                }
            }
            __syncthreads();   // make writes visible (and fence the compiler)
            #pragma unroll
            for (int kt = 0; kt < 8; ++kt)
                afrag[kt] = *(const v8s*)((const unsigned char*)scr
                                          + (lr * 256 + kt * 32 + g * 8) * 2);
        } else {
            // fused output layer: bases[m] = sum_h z[m][h]*W_out[n][h] + b_out
            const float* wo = W_out + (size_t)n * HDIM;
            float ps[4] = {0, 0, 0, 0};
            #pragma unroll
            for (int ct = 0; ct < 16; ++ct) {
                const float a_ = la[ct * 16 + lr], b_ = lb[ct * 16 + lr];
                const float w_ = wo[ct * 16 + lr];
                #pragma unroll
                for (int r = 0; r < 4; ++r) {
                    float v = acc[ct][r];
                    float s = selu_f(v + (v - mean[r]) * inv[r] * a_ + b_);
                    ps[r] += s * w_;
                }
            }
            #pragma unroll
            for (int r = 0; r < 4; ++r)
                #pragma unroll
                for (int msk = 1; msk <= 8; msk <<= 1)
                    ps[r] += __shfl_xor(ps[r], msk);
            const float bo = b_out[n];
            #pragma unroll
            for (int r = 0; r < 4; ++r)
                if (lr == r)
                    basesT[(size_t)(wv * 16 + g * 4 + r) * NNET + n] = ps[r] + bo;
        }
    }
}

// score[b, jk] = sum_m x[b,m,jk>>1] * basesT[m][jk] * w[m]
// block: 32 jk-lanes x 8 batch rows; bases*w slice staged in LDS once.
__launch_bounds__(256)
__global__ void score_kernel(const float* __restrict__ x,
                             const float* __restrict__ t,
                             const float* __restrict__ basesT,
                             float* __restrict__ out)
{
    __shared__ float c_lds[M_GRID * 32];
    const int jt  = blockIdx.x;   // 0..4
    const int bt  = blockIdx.y;   // 0..255
    const int tid = threadIdx.x;

    for (int i = tid; i < M_GRID * 32; i += 256) {
        const int m  = i >> 5;
        const int jl = i & 31;
        const float tp = t[m == M_GRID - 1 ? M_GRID - 1 : m + 1];
        const float tm = t[m == 0 ? 0 : m - 1];
        c_lds[i] = basesT[(size_t)m * NNET + jt * 32 + jl] * 0.5f * (tp - tm);
    }
    __syncthreads();

    const int jj = tid & 31;
    const int bs = tid >> 5;
    const int jk = jt * 32 + jj;
    const int b  = bt * 8 + bs;
    const float* xp = x + (size_t)b * (M_GRID * J_FEAT) + (jk >> 1);
    float acc = 0.f;
    #pragma unroll 8
    for (int m = 0; m < M_GRID; ++m)
        acc += xp[(size_t)m * J_FEAT] * c_lds[m * 32 + jj];
    out[(size_t)b * NNET + jk] = acc;
}

extern "C" void kernel_launch(void* const* d_in, const int* in_sizes, int n_in,
                              void* d_out, int out_size, void* d_ws, size_t ws_size,
                              hipStream_t stream)
{
    const float* x     = (const float*)d_in[0];
    const float* t     = (const float*)d_in[1];
    const float* W_in  = (const float*)d_in[2];
    const float* b_in  = (const float*)d_in[3];
    const float* W_h   = (const float*)d_in[4];
    const float* b_h   = (const float*)d_in[5];
    const float* W_out = (const float*)d_in[6];
    const float* b_out = (const float*)d_in[7];
    const float* ln_a  = (const float*)d_in[8];
    const float* ln_b  = (const float*)d_in[9];
    float* basesT = (float*)d_ws;   // 128*160*4 = 80 KiB

    basis_kernel<<<dim3(NNET), dim3(512), 0, stream>>>(
        t, W_in, b_in, W_h, b_h, W_out, b_out, ln_a, ln_b, basesT);
    score_kernel<<<dim3(5, 256), dim3(256), 0, stream>>>(
        x, t, basesT, (float*)d_out);
}